// Round 16
// baseline (1003.510 us; speedup 1.0000x reference)
//
#include <hip/hip_runtime.h>
#include <hip/hip_bf16.h>
#include <math.h>

#define BB 8
#define NN 256
#define DD 384
#define LL 6
#define HH 8
#define FFD 1536
#define TT 4
#define DH 48
#define NM1 517      // T + 1 + 2N
#define SS 1034      // 2 * NM1
#define SSP 1088     // padded key stride for vt (17*64)
#define MROWS (BB*SS)
#define NQKV 1152
// Q pre-scale folds 1/sqrt(48) AND log2(e): softmax runs in exp2 domain.
#define QSCALE2 (0.14433756729740643f * 1.4426950408889634f)

typedef unsigned short u16;
typedef unsigned int u32;
typedef short bf8 __attribute__((ext_vector_type(8)));
typedef float f32x4 __attribute__((ext_vector_type(4)));

__device__ __forceinline__ u16 f2bf(float f) {
  __hip_bfloat16 h = __float2bfloat16(f);
  return *reinterpret_cast<u16*>(&h);
}
__device__ __forceinline__ float bf2f(u16 u) {
  __hip_bfloat16 h;
  *reinterpret_cast<u16*>(&h) = u;
  return __bfloat162float(h);
}
__device__ __forceinline__ float max3f(float a, float b, float c) {
  return fmaxf(fmaxf(a, b), c);   // clang fuses to v_max3_f32
}
// async global->LDS, 16B per lane; lds dest wave-uniform (HW adds lane*16)
__device__ __forceinline__ void async16(void* lds, const void* g) {
  __builtin_amdgcn_global_load_lds(
      (const __attribute__((address_space(1))) unsigned int*)g,
      (__attribute__((address_space(3))) unsigned int*)lds, 16, 0, 0);
}

// ---------------------------------------------------------------------------
// src assembly: fp32 residual + bf16 mirror.
// ---------------------------------------------------------------------------
__global__ void build_src(const float* __restrict__ hand_t, const float* __restrict__ head_t,
                          const float* __restrict__ hand_m1, const float* __restrict__ head_m1,
                          const float* __restrict__ state_t, const float* __restrict__ state_m1,
                          const float* __restrict__ tok_m1, const float* __restrict__ tok_t,
                          float* __restrict__ src, u16* __restrict__ srcb) {
  int idx = blockIdx.x * 256 + threadIdx.x;
  if (idx >= BB * SS * DD) return;
  int d = idx % DD;
  int bs = idx / DD;
  int s = bs % SS;
  int b = bs / SS;
  float val;
  if (s == 0)               val = state_m1[b * DD + d];
  else if (s <= NN)         val = hand_m1[((size_t)(b * NN + (s - 1))) * DD + d];
  else if (s <= 2 * NN)     val = head_m1[((size_t)(b * NN + (s - 1 - NN))) * DD + d];
  else if (s <= 2 * NN + TT) val = tok_m1[(s - (2 * NN + 1)) * DD + d];
  else if (s == NM1)        val = state_t[b * DD + d];
  else if (s <= NM1 + NN)   val = hand_t[((size_t)(b * NN + (s - NM1 - 1))) * DD + d];
  else if (s <= NM1 + 2 * NN) val = head_t[((size_t)(b * NN + (s - NM1 - 1 - NN))) * DD + d];
  else                      val = tok_t[(s - (NM1 + 2 * NN + 1)) * DD + d];
  src[idx] = val;
  srcb[idx] = f2bf(val);
}

__global__ void build_coords(const float* __restrict__ c_hand_t, const float* __restrict__ c_head_t,
                             const float* __restrict__ c_hand_m1, const float* __restrict__ c_head_m1,
                             const float* __restrict__ tr_t, const float* __restrict__ tr_m1,
                             float* __restrict__ coords) {
  int idx = blockIdx.x * 256 + threadIdx.x;
  if (idx >= BB * SS * 3) return;
  int a = idx % 3;
  int bs = idx / 3;
  int s = bs % SS;
  int b = bs / SS;
  float val;
  if (s == 0)               val = tr_m1[b * 3 + a];
  else if (s <= NN)         val = c_hand_m1[(b * NN + (s - 1)) * 3 + a];
  else if (s <= 2 * NN)     val = c_head_m1[(b * NN + (s - 1 - NN)) * 3 + a];
  else if (s <= 2 * NN + TT) val = tr_m1[b * 3 + a];
  else if (s == NM1)        val = tr_t[b * 3 + a];
  else if (s <= NM1 + NN)   val = c_hand_t[(b * NN + (s - NM1 - 1)) * 3 + a];
  else if (s <= NM1 + 2 * NN) val = c_head_t[(b * NN + (s - NM1 - 1 - NN)) * 3 + a];
  else                      val = tr_t[b * 3 + a];
  coords[idx] = val;
}

// cos/sin table: trig[(b*SS+s)*24 + axis*8 + i] = {cos, sin}(coords*inv_freq)
__global__ void build_trig(const float* __restrict__ coords, float2* __restrict__ trig) {
  int idx = blockIdx.x * 256 + threadIdx.x;
  if (idx >= BB * SS * 24) return;
  int i = idx & 7;
  int axis = (idx >> 3) % 3;
  int bs = idx / 24;
  float cv = coords[bs * 3 + axis];
  float inv = expf(-(float)i * 1.1512925464970229f);  // 10000^(-i/8)
  float ang = cv * inv;
  trig[idx] = make_float2(cosf(ang), sinf(ang));
}

// ---------------------------------------------------------------------------
// weight conversion / packing (LN gamma folded into Wqkv[l>=1] and W1)
// ---------------------------------------------------------------------------
__global__ void cvt_bf(const float* __restrict__ in, u16* __restrict__ out, int n4) {
  int idx = blockIdx.x * 256 + threadIdx.x;
  if (idx >= n4) return;
  float4 v = reinterpret_cast<const float4*>(in)[idx];
  short4 o;
  o.x = (short)f2bf(v.x); o.y = (short)f2bf(v.y);
  o.z = (short)f2bf(v.z); o.w = (short)f2bf(v.w);
  reinterpret_cast<short4*>(out)[idx] = o;
}

// wqkvf[l][n][k] = bf16( W[n][k] * (l==0 ? 1 : g2[l-1][k]) )
__global__ void pack_qkv(const float* __restrict__ Wq, const float* __restrict__ Wk,
                         const float* __restrict__ Wv, const float* __restrict__ g2,
                         u16* __restrict__ wqkv) {
  int idx = blockIdx.x * 256 + threadIdx.x;
  const int TOTAL = LL * NQKV * 96;
  if (idx >= TOTAL) return;
  int k4 = idx % 96;
  int n = (idx / 96) % NQKV;
  int l = idx / (96 * NQKV);
  int sel = n / 384, nn = n - sel * 384;
  const float* W = (sel == 0) ? Wq : ((sel == 1) ? Wk : Wv);
  float4 v = *reinterpret_cast<const float4*>(W + ((size_t)l * 384 + nn) * 384 + k4 * 4);
  float4 gg = make_float4(1.f, 1.f, 1.f, 1.f);
  if (l > 0) gg = *reinterpret_cast<const float4*>(g2 + (size_t)(l - 1) * 384 + k4 * 4);
  short4 o;
  o.x = (short)f2bf(v.x * gg.x); o.y = (short)f2bf(v.y * gg.y);
  o.z = (short)f2bf(v.z * gg.z); o.w = (short)f2bf(v.w * gg.w);
  *reinterpret_cast<short4*>(wqkv + ((size_t)(l * NQKV + n) * 384 + k4 * 4)) = o;
}

// w1f[l][n][k] = bf16( W1[l][n][k] * g1[l][k] )
__global__ void pack_w1(const float* __restrict__ W1, const float* __restrict__ g1,
                        u16* __restrict__ w1f) {
  int idx = blockIdx.x * 256 + threadIdx.x;
  const int TOTAL = LL * FFD * 96;
  if (idx >= TOTAL) return;
  int k4 = idx % 96;
  int n = (idx / 96) % FFD;
  int l = idx / (96 * FFD);
  float4 v = *reinterpret_cast<const float4*>(W1 + ((size_t)l * FFD + n) * 384 + k4 * 4);
  float4 gg = *reinterpret_cast<const float4*>(g1 + (size_t)l * 384 + k4 * 4);
  short4 o;
  o.x = (short)f2bf(v.x * gg.x); o.y = (short)f2bf(v.y * gg.y);
  o.z = (short)f2bf(v.z * gg.z); o.w = (short)f2bf(v.w * gg.w);
  *reinterpret_cast<short4*>(w1f + ((size_t)(l * FFD + n) * 384 + k4 * 4)) = o;
}

__global__ void pack_bqkv(const float* __restrict__ bq, const float* __restrict__ bk,
                          const float* __restrict__ bv, float* __restrict__ bqkv) {
  int idx = blockIdx.x * 256 + threadIdx.x;
  if (idx >= LL * NQKV) return;
  int n = idx % NQKV, l = idx / NQKV;
  int sel = n / 384, nn = n - sel * 384;
  const float* Bp = (sel == 0) ? bq : ((sel == 1) ? bk : bv);
  bqkv[idx] = Bp[l * 384 + nn];
}

// G[l][n] = sum_k bf2f(wqkvf) ; C[l][n] = sum_k be2[l-1][k]*W[n][k] + b[n]
__global__ void qkv_consts(const u16* __restrict__ wqkvf,
                           const float* __restrict__ Wq, const float* __restrict__ Wk,
                           const float* __restrict__ Wv, const float* __restrict__ bqkv,
                           const float* __restrict__ be2,
                           float* __restrict__ G, float* __restrict__ C) {
  int gid = blockIdx.x * 4 + (threadIdx.x >> 6);
  int lane = threadIdx.x & 63;
  if (gid >= LL * NQKV) return;
  int l = gid / NQKV, n = gid % NQKV;
  int sel = n / 384, nn = n - sel * 384;
  const float* W = (sel == 0) ? Wq : ((sel == 1) ? Wk : Wv);
  float s = 0.f, c = 0.f;
  for (int k = lane; k < 384; k += 64) {
    s += bf2f(wqkvf[(size_t)gid * 384 + k]);
    float bek = (l == 0) ? 0.f : be2[(l - 1) * 384 + k];
    c += bek * W[((size_t)l * 384 + nn) * 384 + k];
  }
#pragma unroll
  for (int off = 32; off; off >>= 1) { s += __shfl_xor(s, off); c += __shfl_xor(c, off); }
  if (lane == 0) { G[gid] = s; C[gid] = c + bqkv[gid]; }
}

__global__ void w1_consts(const u16* __restrict__ w1f, const float* __restrict__ W1,
                          const float* __restrict__ b1, const float* __restrict__ be1,
                          float* __restrict__ G, float* __restrict__ C) {
  int gid = blockIdx.x * 4 + (threadIdx.x >> 6);
  int lane = threadIdx.x & 63;
  if (gid >= LL * FFD) return;
  int l = gid / FFD, n = gid % FFD;
  float s = 0.f, c = 0.f;
  for (int k = lane; k < 384; k += 64) {
    s += bf2f(w1f[(size_t)gid * 384 + k]);
    c += be1[l * 384 + k] * W1[((size_t)l * FFD + n) * 384 + k];
  }
#pragma unroll
  for (int off = 32; off; off >>= 1) { s += __shfl_xor(s, off); c += __shfl_xor(c, off); }
  if (lane == 0) { G[gid] = s; C[gid] = c + b1[gid]; }
}

// finalize row stats: (sum, sumsq) -> (mu, rsqrt(var+eps)); zero accumulator
__global__ void stats_fin(float* __restrict__ acc, float* __restrict__ fin) {
  int m = blockIdx.x * 256 + threadIdx.x;
  if (m >= MROWS) return;
  float s = acc[2 * m], ss = acc[2 * m + 1];
  float mu = s * (1.0f / 384.0f);
  float var = ss * (1.0f / 384.0f) - mu * mu;
  fin[2 * m] = mu;
  fin[2 * m + 1] = rsqrtf(var + 1e-5f);
  acc[2 * m] = 0.f;
  acc[2 * m + 1] = 0.f;
}

// zero the padded key columns [SS, SSP) of vt
__global__ void pad_vt(u16* __restrict__ vt) {
  int idx = blockIdx.x * 256 + threadIdx.x;
  const int PADW = SSP - SS;
  if (idx >= 64 * DH * PADW) return;
  int c = idx % PADW;
  int rd = idx / PADW;
  vt[(size_t)rd * SSP + SS + c] = 0;
}

// zero the d=48..63 pad of qh/kh (GEMM epilogue writes only d<48)
__global__ void pad_qk(u16* __restrict__ qh, u16* __restrict__ kh) {
  int idx = blockIdx.x * 256 + threadIdx.x;
  if (idx >= 64 * SS * 16) return;
  int c = idx & 15;
  int row = idx >> 4;
  qh[(size_t)row * 64 + 48 + c] = 0;
  kh[(size_t)row * 64 + 48 + c] = 0;
}

// ---------------------------------------------------------------------------
// MFMA GEMM (round-15 verified core): 128x64 tile, 512 threads = 8 waves,
// counted vmcnt(3) dbuf, compile-time N/K, balanced XCD M-stripes.
//   FOLD=1: A is RAW residual; LN folded: v = rs_m*acc + C_n - mu_m*rs_m*G_n.
//   RES: 0 none, 1 fp32 Rf add, 2 inline-LN(RfL, stR, gR, beR) add.
//   OUT: 0 fp32+bf16 residual write + row-stats atomics, 1 bf16,
//        2 fused-QKV + RoPE (LDS [128][65] fp32).
// ---------------------------------------------------------------------------
template <int EPI, int OUT, int Nc, int Kc, int FOLD, int RES>
__global__ __launch_bounds__(512) void gemm_as(
    const u16* __restrict__ Ab, const u16* __restrict__ Wb,
    const float* __restrict__ bias,
    const float* __restrict__ Gv, const float* __restrict__ Cvv,
    const float* __restrict__ stA,
    const float2* __restrict__ trig,
    const float* __restrict__ Rf,
    const float* __restrict__ RfL, const float* __restrict__ stR,
    const float* __restrict__ gR, const float* __restrict__ beR,
    float* __restrict__ Cf, u16* __restrict__ Cb,
    u16* __restrict__ Ck, u16* __restrict__ Cvt,
    float* __restrict__ sAcc) {
  constexpr int BUFSZ = 24576;  // A 16KB + B 8KB
  constexpr int M = MROWS;
  constexpr int nxt = Nc >> 6;
  __shared__ __align__(16) char sm[2 * BUFSZ];   // 48KB; OUT==2 reuses as fp32 [128][65]
  const int tid = threadIdx.x;

  // balanced XCD M-stripe decomposition: XCD0 -> 9 tiles, XCD1..7 -> 8 tiles
  const int gL = blockIdx.x;
  const int x8 = gL & 7, jj = gL >> 3;
  const int jjm = jj / nxt;                       // slot within XCD (0..8)
  const int cnt = (x8 == 0) ? 9 : 8;
  if (jjm >= cnt) return;
  const int mt_ = ((x8 == 0) ? 0 : 9 + (x8 - 1) * 8) + jjm;
  const int bm = mt_ << 7, bn = (jj % nxt) << 6;

  const int lid = tid & 63, w = tid >> 6;        // w in 0..7
  const int wm = w >> 1, wn = w & 1;             // wave owns (wm*32, wn*32) 32x32
  const int l15 = lid & 15, lg = lid >> 4;
  const int lr = lid >> 3, lu = lid & 7;
  const int swz = lu ^ lr;
  f32x4 acc[2][2] = {};

  auto stage = [&](int bsel, int k0) {
    char* base = sm + bsel * BUFSZ;
#pragma unroll
    for (int q = 0; q < 2; ++q) {
      int row = w * 16 + q * 8 + lr;
      int grow = bm + row; if (grow >= M) grow = M - 1;
      async16(base + w * 2048 + q * 1024, Ab + (size_t)grow * Kc + k0 + (swz << 3));
    }
    async16(base + 16384 + w * 1024, Wb + (size_t)(bn + w * 8 + lr) * Kc + k0 + (swz << 3));
  };

  stage(0, 0);   // 3 loads in flight per wave
  int bs = 0;

#pragma unroll
  for (int k0 = 0; k0 < Kc; k0 += 64) {
    if (k0 + 64 < Kc) {
      stage(bs ^ 1, k0 + 64);
      asm volatile("s_waitcnt vmcnt(3)" ::: "memory");
    } else {
      asm volatile("s_waitcnt vmcnt(0)" ::: "memory");
    }
    __builtin_amdgcn_s_barrier();
    const char* base = sm + bs * BUFSZ;
    bf8 a[2][2], bfr[2][2];
#pragma unroll
    for (int kf = 0; kf < 2; ++kf) {
#pragma unroll
      for (int mt = 0; mt < 2; ++mt) {
        int row = wm * 32 + mt * 16 + l15;
        int off = ((row << 7) + (kf << 6) + (lg << 4)) ^ ((row & 7) << 4);
        a[kf][mt] = *reinterpret_cast<const bf8*>(base + off);
      }
#pragma unroll
      for (int nt = 0; nt < 2; ++nt) {
        int row = wn * 32 + nt * 16 + l15;
        int off = 16384 + (((row << 7) + (kf << 6) + (lg << 4)) ^ ((row & 7) << 4));
        bfr[kf][nt] = *reinterpret_cast<const bf8*>(base + off);
      }
    }
#pragma unroll
    for (int kf = 0; kf < 2; ++kf)
#pragma unroll
      for (int mt = 0; mt < 2; ++mt)
#pragma unroll
        for (int nt = 0; nt < 2; ++nt)
          acc[mt][nt] = __builtin_amdgcn_mfma_f32_16x16x32_bf16(a[kf][mt], bfr[kf][nt], acc[mt][nt], 0, 0, 0);
    asm volatile("s_waitcnt lgkmcnt(0)" ::: "memory");
    __builtin_amdgcn_s_barrier();
    bs ^= 1;
  }

  if constexpr (OUT == 1) {
#pragma unroll
    for (int nt = 0; nt < 2; ++nt) {
      const int n = bn + wn * 32 + nt * 16 + l15;
#pragma unroll
      for (int mt = 0; mt < 2; ++mt) {
        const int m0 = bm + wm * 32 + mt * 16 + lg * 4;
#pragma unroll
        for (int r = 0; r < 4; ++r) {
          int m = m0 + r;
          if (m >= M) continue;
          float v;
          if constexpr (FOLD) {
            float mu = stA[2 * m], rsv = stA[2 * m + 1];
            v = rsv * acc[mt][nt][r] + Cvv[n] - mu * rsv * Gv[n];
          } else {
            v = acc[mt][nt][r] + bias[n];
          }
          if (EPI == 1) v = 0.5f * v * (1.0f + erff(v * 0.70710678118654752f));
          Cb[(size_t)m * Nc + n] = f2bf(v);
        }
      }
    }
  } else if constexpr (OUT == 0) {
    float vv[2][2][4];
#pragma unroll
    for (int nt = 0; nt < 2; ++nt) {
      const int n = bn + wn * 32 + nt * 16 + l15;
#pragma unroll
      for (int mt = 0; mt < 2; ++mt) {
        const int m0 = bm + wm * 32 + mt * 16 + lg * 4;
#pragma unroll
        for (int r = 0; r < 4; ++r) {
          int m = m0 + r;
          int mc = (m < M) ? m : (M - 1);
          float v;
          if constexpr (FOLD) {
            float mu = stA[2 * mc], rsv = stA[2 * mc + 1];
            v = rsv * acc[mt][nt][r] + Cvv[n] - mu * rsv * Gv[n];
          } else {
            v = acc[mt][nt][r] + bias[n];
          }
          if (EPI == 1) v = 0.5f * v * (1.0f + erff(v * 0.70710678118654752f));
          if constexpr (RES == 1) {
            v += Rf[(size_t)mc * Nc + n];
          } else if constexpr (RES == 2) {
            float x = RfL[(size_t)mc * Nc + n];
            float muR = stR[2 * mc], rsR = stR[2 * mc + 1];
            v += (x - muR) * rsR * gR[n] + beR[n];
          }
          vv[mt][nt][r] = v;
          if (m < M) {
            Cf[(size_t)m * Nc + n] = v;
            Cb[(size_t)m * Nc + n] = f2bf(v);
          }
        }
      }
    }
    // per-row partial stats -> cross-l15 reduce -> atomics
#pragma unroll
    for (int mt = 0; mt < 2; ++mt)
#pragma unroll
      for (int r = 0; r < 4; ++r) {
        int m = bm + wm * 32 + mt * 16 + lg * 4 + r;
        float s = vv[mt][0][r] + vv[mt][1][r];
        float ss = vv[mt][0][r] * vv[mt][0][r] + vv[mt][1][r] * vv[mt][1][r];
        s += __shfl_xor(s, 1);  ss += __shfl_xor(ss, 1);
        s += __shfl_xor(s, 2);  ss += __shfl_xor(ss, 2);
        s += __shfl_xor(s, 4);  ss += __shfl_xor(ss, 4);
        s += __shfl_xor(s, 8);  ss += __shfl_xor(ss, 8);
        if (l15 == 0 && m < M) {
          atomicAdd(&sAcc[2 * m], s);
          atomicAdd(&sAcc[2 * m + 1], ss);
        }
      }
  } else {
    // ---- fused-QKV epilogue: fp32 LDS transpose tile [128][65] ----
    float* tile = (float*)sm;
#pragma unroll
    for (int nt = 0; nt < 2; ++nt) {
      const int nl = wn * 32 + nt * 16 + l15;
      const int n = bn + nl;
#pragma unroll
      for (int mt = 0; mt < 2; ++mt) {
#pragma unroll
        for (int r = 0; r < 4; ++r) {
          int ml = wm * 32 + mt * 16 + lg * 4 + r;
          float v;
          if constexpr (FOLD) {
            int mc = bm + ml; if (mc >= M) mc = M - 1;
            float mu = stA[2 * mc], rsv = stA[2 * mc + 1];
            v = rsv * acc[mt][nt][r] + Cvv[n] - mu * rsv * Gv[n];
          } else {
            v = acc[mt][nt][r] + bias[n];
          }
          tile[ml * 65 + nl] = v;
        }
      }
    }
    __syncthreads();
    const int bnm = bn % 384;
    const int sel = bn / 384;   // uniform per block (384 % 64 == 0)
    if (sel < 2) {
      u16* Cqk = (sel == 0) ? Cb : Ck;
      const int d = lid;
      const int nn_ = bnm + d;
      const int hdiv = nn_ / 48, hrem = nn_ - hdiv * 48;
      const int axis = hrem >> 4, ii = hrem & 7;
      const bool hi = (hrem & 8) != 0;
      for (int si = 0; si < 16; ++si) {
        int row = w * 16 + si;
        int m = bm + row;
        if (m >= M) break;
        int bI = m / SS, s = m - bI * SS;
        float v = tile[row * 65 + d];
        float p = tile[row * 65 + (d ^ 8)];
        float2 t = trig[(size_t)(bI * SS + s) * 24 + axis * 8 + ii];
        float outv = hi ? (p * t.y + v * t.x) : (v * t.x - p * t.y);
        if (sel == 0) outv *= QSCALE2;
        Cqk[((size_t)(bI * HH + hdiv) * SS + s) * 64 + hrem] = f2bf(outv);
      }
    } else {
      const int srow = tid & 127, dq = tid >> 7;
      const int m = bm + srow;
      if (m < M) {
        int bI = m / SS, s = m - bI * SS;
        for (int di = 0; di < 16; ++di) {
          int d = dq * 16 + di;
          int nn_ = bnm + d;
          int hdiv = nn_ / 48, hrem = nn_ - hdiv * 48;
          Cvt[((size_t)(bI * HH + hdiv) * DH + hrem) * SSP + s] = f2bf(tile[srow * 65 + d]);
        }
      }
    }
  }
}

// ---------------------------------------------------------------------------
// Flash attention v8 (round-12 verified) — unchanged.
// ---------------------------------------------------------------------------
__global__ __launch_bounds__(512) void attn_mfma(const u16* __restrict__ qh,
                                                 const u16* __restrict__ kh,
                                                 const u16* __restrict__ vt,
                                                 u16* __restrict__ outb) {
  __shared__ __align__(16) char sm[32768];
  const int tid = threadIdx.x;
  const int lid = tid & 63, w = tid >> 6;     // w in 0..7
  const int l15 = lid & 15, lg = lid >> 4;
  const int lr = lid >> 3, lu = lid & 7;
  const int swz8 = (lu ^ lr) << 3;

  const int f = blockIdx.x;
  const int low = f & 7, j = f >> 3;
  const int gi = j / 9, qp = j - gi * 9;
  const int g = gi * 8 + low;          // (b,h) group
  const int h = g & 7, b = g >> 3;
  const int qblk = (qp < 5) ? (4 + qp) : (qp - 5);  // long (17-chunk) first
  const int bh = b * HH + h;
  const int q0w = qblk * 128 + w * 16;
  const u16* kbase = kh + (size_t)bh * SS * 64;
  const u16* vbase = vt + (size_t)bh * DH * SSP;

  bf8 qf[2];
  {
    int row = q0w + l15; if (row >= SS) row = SS - 1;
    const u16* qp_ = qh + ((size_t)bh * SS + row) * 64;
    qf[0] = *reinterpret_cast<const bf8*>(qp_ + lg * 8);
    qf[1] = *reinterpret_cast<const bf8*>(qp_ + 32 + lg * 8);
  }
  const int qrow = q0w + l15;

  float m_q = -1e30f, l_q = 0.f;
  f32x4 accO[3] = {};

  const int nch = (qblk < 4) ? 9 : 17;

  auto stage = [&](int bsel, int c) {
    const int j0 = c * 64;
    char* kb = sm + bsel * 16384;
    char* vb = kb + 8192;
    {
      int s = w * 8 + lr;
      int jt_ = s >> 4, lgs = (s >> 2) & 3, rr = s & 3;
      int p = ((jt_ >> 1) << 5) + (lgs << 3) + ((jt_ & 1) << 2) + rr;  // pi(s)
      int jrow = j0 + p; if (jrow >= SS) jrow = SS - 1;
      async16(kb + w * 1024, kbase + (size_t)jrow * 64 + swz8);
    }
    {
      int vrow = w * 8 + lr; if (vrow >= DH) vrow = DH - 1;
      async16(vb + w * 1024, vbase + (size_t)vrow * SSP + j0 + swz8);
    }
  };

  stage(0, 0);
  __syncthreads();
  int bsel = 0;

  for (int c = 0; c < nch; ++c) {
    if (c + 1 < nch) {
      stage(bsel ^ 1, c + 1);
      asm volatile("s_waitcnt vmcnt(2)" ::: "memory");
    } else {
      asm volatile("s_waitcnt vmcnt(0)" ::: "memory");
    }
    __builtin_amdgcn_s_barrier();
    const int j0 = c * 64;
    const char* kb = sm + bsel * 16384;
    const char* vb = kb + 8192;

    f32x4 sv[4];
    __builtin_amdgcn_s_setprio(1);
#pragma unroll
    for (int jt = 0; jt < 4; ++jt) {
      int row = jt * 16 + l15;
      int off0 = ((row << 7) + (lg << 4)) ^ ((row & 7) << 4);
      int off1 = ((row << 7) + 64 + (lg << 4)) ^ ((row & 7) << 4);
      bf8 kb0 = *reinterpret_cast<const bf8*>(kb + off0);
      bf8 kb1 = *reinterpret_cast<const bf8*>(kb + off1);
      f32x4 z = {};
      z = __builtin_amdgcn_mfma_f32_16x16x32_bf16(kb0, qf[0], z, 0, 0, 0);
      z = __builtin_amdgcn_mfma_f32_16x16x32_bf16(kb1, qf[1], z, 0, 0, 0);
      sv[jt] = z;
    }
    __builtin_amdgcn_s_setprio(0);

    const bool domask = (c == 16) | ((q0w < NM1) & (c >= 8));
    if (domask) {
#pragma unroll
      for (int jt = 0; jt < 4; ++jt)
#pragma unroll
        for (int r = 0; r < 4; ++r) {
          int kabs = j0 + ((jt >> 1) << 5) + (lg << 3) + ((jt & 1) << 2) + r;
          if (kabs >= SS || (qrow < NM1 && kabs >= NM1)) sv[jt][r] = -1e30f;
        }
    }

    float mx = max3f(sv[0][0], sv[0][1], sv[0][2]);
    mx = max3f(mx, sv[0][3], sv[1][0]);
    mx = max3f(mx, sv[1][1], sv[1][2]);
    mx = max3f(mx, sv[1][3], sv[2][0]);
    mx = max3f(mx, sv[2][1], sv[2][2]);
    mx = max3f(mx, sv[2][3], sv[3][0]);
    mx = max3f(mx, sv[3][1], sv[3][2]);
    mx = fmaxf(mx, sv[3][3]);
    mx = fmaxf(mx, __shfl_xor(mx, 16));
    mx = fmaxf(mx, __shfl_xor(mx, 32));

    const bool skip = __all(mx <= m_q);
    const float mn = skip ? m_q : fmaxf(m_q, mx);

    float pv[4][4];
    float ps = 0.f;
#pragma unroll
    for (int jt = 0; jt < 4; ++jt)
#pragma unroll
      for (int r = 0; r < 4; ++r) {
        float p = __builtin_amdgcn_exp2f(sv[jt][r] - mn);
        pv[jt][r] = p;
        ps += p;
      }
    ps += __shfl_xor(ps, 16);
    ps += __shfl_xor(ps, 32);

    if (!skip) {
      float alpha = __builtin_amdgcn_exp2f(m_q - mn);
      l_q = l_q * alpha + ps;
      m_q = mn;
      const int lg4 = lg * 4;
      float a0 = __shfl(alpha, lg4);
      float a1 = __shfl(alpha, lg4 + 1);
      float a2 = __shfl(alpha, lg4 + 2);
      float a3 = __shfl(alpha, lg4 + 3);
#pragma unroll
      for (int dt = 0; dt < 3; ++dt) {
        accO[dt][0] *= a0; accO[dt][1] *= a1;
        accO[dt][2] *= a2; accO[dt][3] *= a3;
      }
    } else {
      l_q += ps;
    }

    bf8 pa[2];
#pragma unroll
    for (int jc = 0; jc < 2; ++jc) {
      u32 w0 = (u32)f2bf(pv[jc * 2][0])     | ((u32)f2bf(pv[jc * 2][1]) << 16);
      u32 w1 = (u32)f2bf(pv[jc * 2][2])     | ((u32)f2bf(pv[jc * 2][3]) << 16);
      u32 w2 = (u32)f2bf(pv[jc * 2 + 1][0]) | ((u32)f2bf(pv[jc * 2 + 1][1]) << 16);
      u32 w3 = (u32)f2bf(pv[jc * 2 + 1][2]) | ((u32)f2bf(pv[jc * 2 + 1][3]) << 16);
      uint4 t = make_uint4(w0, w1, w2, w3);
      pa[jc] = *reinterpret_cast<bf8*>(&t);
    }

    __builtin_amdgcn_s_setprio(1);
#pragma unroll
    for (int dt = 0; dt < 3; ++dt) {
      int row = dt * 16 + l15;
#pragma unroll
      for (int jc = 0; jc < 2; ++jc) {
        int off = ((row << 7) + (jc << 6) + (lg << 4)) ^ ((row & 7) << 4);
        bf8 vb8 = *reinterpret_cast<const bf8*>(vb + off);
        accO[dt] = __builtin_amdgcn_mfma_f32_16x16x32_bf16(pa[jc], vb8, accO[dt], 0, 0, 0);
      }
    }
    __builtin_amdgcn_s_setprio(0);
    asm volatile("s_waitcnt lgkmcnt(0)" ::: "memory");
    __builtin_amdgcn_s_barrier();
    bsel ^= 1;
  }

  float linv = 1.0f / l_q;
  const int lg4 = lg * 4;
  float il[4];
#pragma unroll
  for (int r = 0; r < 4; ++r) il[r] = __shfl(linv, lg4 + r);
#pragma unroll
  for (int r = 0; r < 4; ++r) {
    int q = q0w + lg4 + r;
    if (q >= SS) continue;
#pragma unroll
    for (int dt = 0; dt < 3; ++dt) {
      int d = dt * 16 + l15;
      outb[((size_t)(b * SS + q)) * DD + h * DH + d] = f2bf(accO[dt][r] * il[r]);
    }
  }
}

// final output: out = LN2_last(rf2 rows)
__global__ void copy_out(const float* __restrict__ rf2, const float* __restrict__ st,
                         const float* __restrict__ g, const float* __restrict__ be,
                         float* __restrict__ out) {
  int idx = blockIdx.x * 256 + threadIdx.x;
  if (idx >= BB * TT * DD) return;
  int d = idx % DD;
  int bt = idx / DD;
  int t = bt % TT;
  int b = bt / TT;
  int m = b * SS + (SS - TT) + t;
  float mu = st[2 * m], rs = st[2 * m + 1];
  out[idx] = (rf2[(size_t)m * DD + d] - mu) * rs * g[d] + be[d];
}

// ---------------------------------------------------------------------------
extern "C" void kernel_launch(void* const* d_in, const int* in_sizes, int n_in,
                              void* d_out, int out_size, void* d_ws, size_t ws_size,
                              hipStream_t stream) {
  const float* hand_t    = (const float*)d_in[0];
  const float* head_t    = (const float*)d_in[1];
  const float* hand_m1   = (const float*)d_in[2];
  const float* head_m1   = (const float*)d_in[3];
  const float* c_hand_t  = (const float*)d_in[4];
  const float* c_head_t  = (const float*)d_in[5];
  const float* c_hand_m1 = (const float*)d_in[6];
  const float* c_head_m1 = (const float*)d_in[7];
  const float* state_t   = (const float*)d_in[8];
  const float* state_m1  = (const float*)d_in[9];
  const float* tr_t      = (const float*)d_in[10];
  const float* tr_m1     = (const float*)d_in[11];
  const float* tok_m1    = (const float*)d_in[12];
  const float* tok_t     = (const float*)d_in[13];
  const float* Wq = (const float*)d_in[14];
  const float* bq = (const float*)d_in[15];
  const float* Wk = (const float*)d_in[16];
  const float* bk = (const float*)d_in[17];
  const float* Wv = (const float*)d_in[18];
  const float* bv = (const float*)d_in[19];
  const float* Wo = (const float*)d_in[20];
  const float* bo = (const float*)d_in[21];
  const float* W1 = (const float*)d_in[22];
  const float* b1 = (const float*)d_in[23];
  const float* W2 = (const float*)d_in[24];
  const float* b2 = (const float*)d_in[25];
  const float* g1 = (const float*)d_in[26];
  const float* be1 = (const float*)d_in[27];
  const float* g2 = (const float*)d_in[28];
  const float* be2 = (const float*)d_in[29];

  const size_t SRC_N = (size_t)BB * SS * DD;       // 3,176,448
  float* src    = (float*)d_ws;                    // layer-0 input (fp32)
  float* rf1    = src + SRC_N;                     // pre-LN1 residual
  float* rf2    = rf1 + SRC_N;                     // pre-LN2 residual
  float* coords = rf2 + SRC_N;                     // 24,816
  float* bqkv   = coords + (size_t)BB * SS * 3;    // L*1152
  float* sAcc1  = bqkv + (size_t)LL * NQKV;        // [MROWS][2]
  float* sAcc2  = sAcc1 + 2 * MROWS;
  float* stF1   = sAcc2 + 2 * MROWS;
  float* stF2   = stF1 + 2 * MROWS;
  float* Gq     = stF2 + 2 * MROWS;                // [LL][NQKV]
  float* Cq     = Gq + (size_t)LL * NQKV;
  float* G1     = Cq + (size_t)LL * NQKV;          // [LL][FFD]
  float* C1     = G1 + (size_t)LL * FFD;
  float2* trig  = (float2*)(C1 + (size_t)LL * FFD);  // B*S*24 float2
  u16* srcb  = (u16*)(trig + (size_t)BB * SS * 24);
  u16* rb1   = srcb + SRC_N;
  u16* rb2   = rb1 + SRC_N;
  u16* attnb = rb2 + SRC_N;
  u16* qh  = attnb + SRC_N;
  const size_t QH_N = (size_t)BB * HH * SS * 64;   // 4,233,216
  u16* khb = qh + QH_N;
  u16* vtb = khb + QH_N;                           // 64*48*1088
  u16* hbf = vtb + (size_t)64 * DH * SSP;          // 12,705,792
  u16* wqkv_b = hbf + (size_t)MROWS * FFD;
  const size_t WD = (size_t)LL * DD * DD;
  const size_t WF = (size_t)LL * FFD * DD;
  u16* wo_bf = wqkv_b + (size_t)LL * NQKV * 384;
  u16* w1_bf = wo_bf + WD;
  u16* w2_bf = w1_bf + WF;

  dim3 blk(256);
  dim3 blk512(512);

  hipMemsetAsync(sAcc1, 0, 4 * MROWS * sizeof(float), stream);  // sAcc1+sAcc2

  build_src<<<(BB * SS * DD + 255) / 256, blk, 0, stream>>>(
      hand_t, head_t, hand_m1, head_m1, state_t, state_m1, tok_m1, tok_t, src, srcb);
  build_coords<<<(BB * SS * 3 + 255) / 256, blk, 0, stream>>>(
      c_hand_t, c_head_t, c_hand_m1, c_head_m1, tr_t, tr_m1, coords);
  build_trig<<<(BB * SS * 24 + 255) / 256, blk, 0, stream>>>(coords, trig);
  pack_qkv<<<(LL * NQKV * 96 + 255) / 256, blk, 0, stream>>>(Wq, Wk, Wv, g2, wqkv_b);
  pack_bqkv<<<(LL * NQKV + 255) / 256, blk, 0, stream>>>(bq, bk, bv, bqkv);
  pack_w1<<<(LL * FFD * 96 + 255) / 256, blk, 0, stream>>>(W1, g1, w1_bf);
  cvt_bf<<<(int)(WD / 4 + 255) / 256, blk, 0, stream>>>(Wo, wo_bf, (int)(WD / 4));
  cvt_bf<<<(int)(WF / 4 + 255) / 256, blk, 0, stream>>>(W2, w2_bf, (int)(WF / 4));
  qkv_consts<<<(LL * NQKV + 3) / 4, blk, 0, stream>>>(wqkv_b, Wq, Wk, Wv, bqkv, be2, Gq, Cq);
  w1_consts<<<(LL * FFD + 3) / 4, blk, 0, stream>>>(w1_bf, W1, b1, be1, G1, C1);
  pad_vt<<<(64 * DH * (SSP - SS) + 255) / 256, blk, 0, stream>>>(vtb);
  pad_qk<<<(64 * SS * 16 + 255) / 256, blk, 0, stream>>>(qh, khb);

  dim3 gqkv(18 * 72);   // N=1152
  dim3 gwo(6 * 72);     // N=384
  dim3 gf1(24 * 72);    // N=1536
  dim3 gf2(6 * 72);     // N=384
  dim3 gattn(9 * 8 * 8);
  dim3 gsf((MROWS + 255) / 256);

  for (int l = 0; l < LL; ++l) {
    const u16* Wqkv_l = wqkv_b + (size_t)l * NQKV * 384;
    const u16* Wo_l = wo_bf + (size_t)l * DD * DD;
    const u16* W1_l = w1_bf + (size_t)l * FFD * DD;
    const u16* W2_l = w2_bf + (size_t)l * DD * FFD;

    if (l == 0) {
      gemm_as<0, 2, NQKV, DD, 0, 0><<<gqkv, blk512, 0, stream>>>(
          srcb, Wqkv_l, bqkv, nullptr, nullptr, nullptr, trig,
          nullptr, nullptr, nullptr, nullptr, nullptr,
          nullptr, qh, khb, vtb, nullptr);
    } else {
      gemm_as<0, 2, NQKV, DD, 1, 0><<<gqkv, blk512, 0, stream>>>(
          rb2, Wqkv_l, nullptr, Gq + (size_t)l * NQKV, Cq + (size_t)l * NQKV, stF2, trig,
          nullptr, nullptr, nullptr, nullptr, nullptr,
          nullptr, qh, khb, vtb, nullptr);
    }
    attn_mfma<<<gattn, blk512, 0, stream>>>(qh, khb, vtb, attnb);
    if (l == 0) {
      gemm_as<0, 0, DD, DD, 0, 1><<<gwo, blk512, 0, stream>>>(
          attnb, Wo_l, bo + l * DD, nullptr, nullptr, nullptr, nullptr,
          src, nullptr, nullptr, nullptr, nullptr,
          rf1, rb1, nullptr, nullptr, sAcc1);
    } else {
      gemm_as<0, 0, DD, DD, 0, 2><<<gwo, blk512, 0, stream>>>(
          attnb, Wo_l, bo + l * DD, nullptr, nullptr, nullptr, nullptr,
          nullptr, rf2, stF2, g2 + (l - 1) * DD, be2 + (l - 1) * DD,
          rf1, rb1, nullptr, nullptr, sAcc1);
    }
    stats_fin<<<gsf, blk, 0, stream>>>(sAcc1, stF1);
    gemm_as<1, 1, FFD, DD, 1, 0><<<gf1, blk512, 0, stream>>>(
        rb1, W1_l, nullptr, G1 + (size_t)l * FFD, C1 + (size_t)l * FFD, stF1, nullptr,
        nullptr, nullptr, nullptr, nullptr, nullptr,
        nullptr, hbf, nullptr, nullptr, nullptr);
    gemm_as<0, 0, DD, FFD, 0, 2><<<gf2, blk512, 0, stream>>>(
        hbf, W2_l, b2 + l * DD, nullptr, nullptr, nullptr, nullptr,
        nullptr, rf1, stF1, g1 + l * DD, be1 + l * DD,
        rf2, rb2, nullptr, nullptr, sAcc2);
    stats_fin<<<gsf, blk, 0, stream>>>(sAcc2, stF2);
  }
  copy_out<<<(BB * TT * DD + 255) / 256, blk, 0, stream>>>(
      rf2, stF2, g2 + 5 * DD, be2 + 5 * DD, (float*)d_out);
}

// Round 17
// 872.447 us; speedup vs baseline: 1.1502x; 1.1502x over previous
//
#include <hip/hip_runtime.h>
#include <hip/hip_bf16.h>
#include <math.h>

#define BB 8
#define NN 256
#define DD 384
#define LL 6
#define HH 8
#define FFD 1536
#define TT 4
#define DH 48
#define NM1 517      // T + 1 + 2N
#define SS 1034      // 2 * NM1
#define SSP 1088     // padded key stride for vt (17*64)
#define MROWS (BB*SS)
#define NQKV 1152
// Q pre-scale folds 1/sqrt(48) AND log2(e): softmax runs in exp2 domain.
#define QSCALE2 (0.14433756729740643f * 1.4426950408889634f)

typedef unsigned short u16;
typedef unsigned int u32;
typedef short bf8 __attribute__((ext_vector_type(8)));
typedef float f32x4 __attribute__((ext_vector_type(4)));

__device__ __forceinline__ u16 f2bf(float f) {
  __hip_bfloat16 h = __float2bfloat16(f);
  return *reinterpret_cast<u16*>(&h);
}
__device__ __forceinline__ float bf2f(u16 u) {
  __hip_bfloat16 h;
  *reinterpret_cast<u16*>(&h) = u;
  return __bfloat162float(h);
}
__device__ __forceinline__ float max3f(float a, float b, float c) {
  return fmaxf(fmaxf(a, b), c);   // clang fuses to v_max3_f32
}
// async global->LDS, 16B per lane; lds dest wave-uniform (HW adds lane*16)
__device__ __forceinline__ void async16(void* lds, const void* g) {
  __builtin_amdgcn_global_load_lds(
      (const __attribute__((address_space(1))) unsigned int*)g,
      (__attribute__((address_space(3))) unsigned int*)lds, 16, 0, 0);
}

// ---------------------------------------------------------------------------
// src assembly: fp32 residual + bf16 mirror.
// ---------------------------------------------------------------------------
__global__ void build_src(const float* __restrict__ hand_t, const float* __restrict__ head_t,
                          const float* __restrict__ hand_m1, const float* __restrict__ head_m1,
                          const float* __restrict__ state_t, const float* __restrict__ state_m1,
                          const float* __restrict__ tok_m1, const float* __restrict__ tok_t,
                          float* __restrict__ src, u16* __restrict__ srcb) {
  int idx = blockIdx.x * 256 + threadIdx.x;
  if (idx >= BB * SS * DD) return;
  int d = idx % DD;
  int bs = idx / DD;
  int s = bs % SS;
  int b = bs / SS;
  float val;
  if (s == 0)               val = state_m1[b * DD + d];
  else if (s <= NN)         val = hand_m1[((size_t)(b * NN + (s - 1))) * DD + d];
  else if (s <= 2 * NN)     val = head_m1[((size_t)(b * NN + (s - 1 - NN))) * DD + d];
  else if (s <= 2 * NN + TT) val = tok_m1[(s - (2 * NN + 1)) * DD + d];
  else if (s == NM1)        val = state_t[b * DD + d];
  else if (s <= NM1 + NN)   val = hand_t[((size_t)(b * NN + (s - NM1 - 1))) * DD + d];
  else if (s <= NM1 + 2 * NN) val = head_t[((size_t)(b * NN + (s - NM1 - 1 - NN))) * DD + d];
  else                      val = tok_t[(s - (NM1 + 2 * NN + 1)) * DD + d];
  src[idx] = val;
  srcb[idx] = f2bf(val);
}

__global__ void build_coords(const float* __restrict__ c_hand_t, const float* __restrict__ c_head_t,
                             const float* __restrict__ c_hand_m1, const float* __restrict__ c_head_m1,
                             const float* __restrict__ tr_t, const float* __restrict__ tr_m1,
                             float* __restrict__ coords) {
  int idx = blockIdx.x * 256 + threadIdx.x;
  if (idx >= BB * SS * 3) return;
  int a = idx % 3;
  int bs = idx / 3;
  int s = bs % SS;
  int b = bs / SS;
  float val;
  if (s == 0)               val = tr_m1[b * 3 + a];
  else if (s <= NN)         val = c_hand_m1[(b * NN + (s - 1)) * 3 + a];
  else if (s <= 2 * NN)     val = c_head_m1[(b * NN + (s - 1 - NN)) * 3 + a];
  else if (s <= 2 * NN + TT) val = tr_m1[b * 3 + a];
  else if (s == NM1)        val = tr_t[b * 3 + a];
  else if (s <= NM1 + NN)   val = c_hand_t[(b * NN + (s - NM1 - 1)) * 3 + a];
  else if (s <= NM1 + 2 * NN) val = c_head_t[(b * NN + (s - NM1 - 1 - NN)) * 3 + a];
  else                      val = tr_t[b * 3 + a];
  coords[idx] = val;
}

// cos/sin table: trig[(b*SS+s)*24 + axis*8 + i] = {cos, sin}(coords*inv_freq)
__global__ void build_trig(const float* __restrict__ coords, float2* __restrict__ trig) {
  int idx = blockIdx.x * 256 + threadIdx.x;
  if (idx >= BB * SS * 24) return;
  int i = idx & 7;
  int axis = (idx >> 3) % 3;
  int bs = idx / 24;
  float cv = coords[bs * 3 + axis];
  float inv = expf(-(float)i * 1.1512925464970229f);  // 10000^(-i/8)
  float ang = cv * inv;
  trig[idx] = make_float2(cosf(ang), sinf(ang));
}

// ---------------------------------------------------------------------------
// weight conversion / packing
// ---------------------------------------------------------------------------
__global__ void cvt_bf(const float* __restrict__ in, u16* __restrict__ out, int n4) {
  int idx = blockIdx.x * 256 + threadIdx.x;
  if (idx >= n4) return;
  float4 v = reinterpret_cast<const float4*>(in)[idx];
  short4 o;
  o.x = (short)f2bf(v.x); o.y = (short)f2bf(v.y);
  o.z = (short)f2bf(v.z); o.w = (short)f2bf(v.w);
  reinterpret_cast<short4*>(out)[idx] = o;
}

__global__ void pack_qkv(const float* __restrict__ Wq, const float* __restrict__ Wk,
                         const float* __restrict__ Wv, u16* __restrict__ wqkv) {
  int idx = blockIdx.x * 256 + threadIdx.x;
  const int TOTAL = LL * NQKV * 96;
  if (idx >= TOTAL) return;
  int k4 = idx % 96;
  int n = (idx / 96) % NQKV;
  int l = idx / (96 * NQKV);
  int sel = n / 384, nn = n - sel * 384;
  const float* W = (sel == 0) ? Wq : ((sel == 1) ? Wk : Wv);
  float4 v = *reinterpret_cast<const float4*>(W + ((size_t)l * 384 + nn) * 384 + k4 * 4);
  short4 o;
  o.x = (short)f2bf(v.x); o.y = (short)f2bf(v.y);
  o.z = (short)f2bf(v.z); o.w = (short)f2bf(v.w);
  *reinterpret_cast<short4*>(wqkv + ((size_t)(l * NQKV + n) * 384 + k4 * 4)) = o;
}

__global__ void pack_bqkv(const float* __restrict__ bq, const float* __restrict__ bk,
                          const float* __restrict__ bv, float* __restrict__ bqkv) {
  int idx = blockIdx.x * 256 + threadIdx.x;
  if (idx >= LL * NQKV) return;
  int n = idx % NQKV, l = idx / NQKV;
  int sel = n / 384, nn = n - sel * 384;
  const float* Bp = (sel == 0) ? bq : ((sel == 1) ? bk : bv);
  bqkv[idx] = Bp[l * 384 + nn];
}

// zero the padded key columns [SS, SSP) of vt
__global__ void pad_vt(u16* __restrict__ vt) {
  int idx = blockIdx.x * 256 + threadIdx.x;
  const int PADW = SSP - SS;
  if (idx >= 64 * DH * PADW) return;
  int c = idx % PADW;
  int rd = idx / PADW;
  vt[(size_t)rd * SSP + SS + c] = 0;
}

// zero the d=48..63 pad of qh/kh (GEMM epilogue writes only d<48)
__global__ void pad_qk(u16* __restrict__ qh, u16* __restrict__ kh) {
  int idx = blockIdx.x * 256 + threadIdx.x;
  if (idx >= 64 * SS * 16) return;
  int c = idx & 15;
  int row = idx >> 4;
  qh[(size_t)row * 64 + 48 + c] = 0;
  kh[(size_t)row * 64 + 48 + c] = 0;
}

// ---------------------------------------------------------------------------
// MFMA GEMM (round-15 verified): 128x64 tile, 512 threads = 8 waves
// (wave owns 32x32), async global->LDS, 2-phase dbuf with COUNTED vmcnt(3),
// compile-time N/K (K-loop unrolled). BALANCED XCD M-stripes: Mt=65 split
// 9,8,8,8,8,8,8,8 across XCDs.
//   OUT: 0 fp32 +residual, 1 bf16, 2 fused-QKV + RoPE (LDS [128][65] fp32).
// ---------------------------------------------------------------------------
template <int EPI, int OUT, int Nc, int Kc>
__global__ __launch_bounds__(512) void gemm_as(
    const u16* __restrict__ Ab, const u16* __restrict__ Wb,
    const float* __restrict__ bias, const float2* __restrict__ trig,
    const float* __restrict__ Rf,
    float* __restrict__ Cf, u16* __restrict__ Cb,
    u16* __restrict__ Ck, u16* __restrict__ Cv) {
  constexpr int BUFSZ = 24576;  // A 16KB + B 8KB
  constexpr int M = MROWS;
  constexpr int nxt = Nc >> 6;
  __shared__ __align__(16) char sm[2 * BUFSZ];   // 48KB; OUT==2 reuses as fp32 [128][65]
  const int tid = threadIdx.x;

  // balanced XCD M-stripe decomposition: XCD0 -> 9 tiles, XCD1..7 -> 8 tiles
  const int gL = blockIdx.x;
  const int x8 = gL & 7, jj = gL >> 3;
  const int jjm = jj / nxt;                       // slot within XCD (0..8)
  const int cnt = (x8 == 0) ? 9 : 8;
  if (jjm >= cnt) return;
  const int mt_ = ((x8 == 0) ? 0 : 9 + (x8 - 1) * 8) + jjm;
  const int bm = mt_ << 7, bn = (jj % nxt) << 6;

  const int lid = tid & 63, w = tid >> 6;        // w in 0..7
  const int wm = w >> 1, wn = w & 1;             // wave owns (wm*32, wn*32) 32x32
  const int l15 = lid & 15, lg = lid >> 4;
  const int lr = lid >> 3, lu = lid & 7;
  const int swz = lu ^ lr;
  f32x4 acc[2][2] = {};

  auto stage = [&](int bsel, int k0) {
    char* base = sm + bsel * BUFSZ;
#pragma unroll
    for (int q = 0; q < 2; ++q) {
      int row = w * 16 + q * 8 + lr;
      int grow = bm + row; if (grow >= M) grow = M - 1;
      async16(base + w * 2048 + q * 1024, Ab + (size_t)grow * Kc + k0 + (swz << 3));
    }
    async16(base + 16384 + w * 1024, Wb + (size_t)(bn + w * 8 + lr) * Kc + k0 + (swz << 3));
  };

  stage(0, 0);   // 3 loads in flight per wave
  int bs = 0;

#pragma unroll
  for (int k0 = 0; k0 < Kc; k0 += 64) {
    if (k0 + 64 < Kc) {
      stage(bs ^ 1, k0 + 64);                           // +3 loads for t+1
      asm volatile("s_waitcnt vmcnt(3)" ::: "memory");  // tile t landed; t+1 in flight
    } else {
      asm volatile("s_waitcnt vmcnt(0)" ::: "memory");
    }
    __builtin_amdgcn_s_barrier();                       // all waves' tile t visible
    const char* base = sm + bs * BUFSZ;
    bf8 a[2][2], bfr[2][2];
#pragma unroll
    for (int kf = 0; kf < 2; ++kf) {
#pragma unroll
      for (int mt = 0; mt < 2; ++mt) {
        int row = wm * 32 + mt * 16 + l15;
        int off = ((row << 7) + (kf << 6) + (lg << 4)) ^ ((row & 7) << 4);
        a[kf][mt] = *reinterpret_cast<const bf8*>(base + off);
      }
#pragma unroll
      for (int nt = 0; nt < 2; ++nt) {
        int row = wn * 32 + nt * 16 + l15;
        int off = 16384 + (((row << 7) + (kf << 6) + (lg << 4)) ^ ((row & 7) << 4));
        bfr[kf][nt] = *reinterpret_cast<const bf8*>(base + off);
      }
    }
#pragma unroll
    for (int kf = 0; kf < 2; ++kf)
#pragma unroll
      for (int mt = 0; mt < 2; ++mt)
#pragma unroll
        for (int nt = 0; nt < 2; ++nt)
          acc[mt][nt] = __builtin_amdgcn_mfma_f32_16x16x32_bf16(a[kf][mt], bfr[kf][nt], acc[mt][nt], 0, 0, 0);
    asm volatile("s_waitcnt lgkmcnt(0)" ::: "memory");  // all LDS reads of buf bs done
    __builtin_amdgcn_s_barrier();                       // WAR: buf bs free for next stage
    bs ^= 1;
  }

  if constexpr (OUT != 2) {
#pragma unroll
    for (int nt = 0; nt < 2; ++nt) {
      const int n = bn + wn * 32 + nt * 16 + l15;
      const float bsv = bias[n];
#pragma unroll
      for (int mt = 0; mt < 2; ++mt) {
        const int m0 = bm + wm * 32 + mt * 16 + lg * 4;
#pragma unroll
        for (int r = 0; r < 4; ++r) {
          int m = m0 + r;
          if (m >= M) continue;
          float v = acc[mt][nt][r] + bsv;
          if (EPI == 1) v = 0.5f * v * (1.0f + erff(v * 0.70710678118654752f));
          if (OUT == 0) Cf[(size_t)m * Nc + n] = v + Rf[(size_t)m * Nc + n];
          else          Cb[(size_t)m * Nc + n] = f2bf(v);
        }
      }
    }
  } else {
    // ---- fused-QKV epilogue: fp32 LDS transpose tile [128][65] ----
    float* tile = (float*)sm;
#pragma unroll
    for (int nt = 0; nt < 2; ++nt) {
      const int nl = wn * 32 + nt * 16 + l15;
      const float bsv = bias[bn + nl];
#pragma unroll
      for (int mt = 0; mt < 2; ++mt) {
#pragma unroll
        for (int r = 0; r < 4; ++r) {
          int ml = wm * 32 + mt * 16 + lg * 4 + r;
          tile[ml * 65 + nl] = acc[mt][nt][r] + bsv;
        }
      }
    }
    __syncthreads();
    const int bnm = bn % 384;
    const int sel = bn / 384;   // uniform per block (384 % 64 == 0)
    if (sel < 2) {
      // lanes span d (coalesced qh/kh row stores); wave w owns rows w*16..+16
      u16* Cqk = (sel == 0) ? Cb : Ck;
      const int d = lid;
      const int nn_ = bnm + d;
      const int hdiv = nn_ / 48, hrem = nn_ - hdiv * 48;
      const int axis = hrem >> 4, ii = hrem & 7;
      const bool hi = (hrem & 8) != 0;
      for (int si = 0; si < 16; ++si) {
        int row = w * 16 + si;
        int m = bm + row;
        if (m >= M) break;
        int bI = m / SS, s = m - bI * SS;
        float v = tile[row * 65 + d];
        float p = tile[row * 65 + (d ^ 8)];
        float2 t = trig[(size_t)(bI * SS + s) * 24 + axis * 8 + ii];
        float outv = hi ? (p * t.y + v * t.x) : (v * t.x - p * t.y);
        if (sel == 0) outv *= QSCALE2;
        Cqk[((size_t)(bI * HH + hdiv) * SS + s) * 64 + hrem] = f2bf(outv);
      }
    } else {
      // V: lanes span s (coalesced vt row stores); 512 thr = 128 rows x 4 d-strips
      const int srow = tid & 127, dq = tid >> 7;
      const int m = bm + srow;
      if (m < M) {
        int bI = m / SS, s = m - bI * SS;
        for (int di = 0; di < 16; ++di) {
          int d = dq * 16 + di;
          int nn_ = bnm + d;
          int hdiv = nn_ / 48, hrem = nn_ - hdiv * 48;
          Cv[((size_t)(bI * HH + hdiv) * DH + hrem) * SSP + s] = f2bf(tile[srow * 65 + d]);
        }
      }
    }
  }
}

// ---------------------------------------------------------------------------
// Flash attention v8 (round-12 verified): QBLK=128, 512 threads (8 waves x
// 16 queries), shared K/V chunks, counted vmcnt(2) double-buffer, swapped
// QK^T + permuted K staging, exp2-domain softmax, max3, setprio, T13 skip.
// ---------------------------------------------------------------------------
__global__ __launch_bounds__(512) void attn_mfma(const u16* __restrict__ qh,
                                                 const u16* __restrict__ kh,
                                                 const u16* __restrict__ vt,
                                                 u16* __restrict__ outb) {
  // buf b: K 8KB @ b*16384, Vt 8KB @ b*16384+8192 (V rows 48..63 are junk pad)
  __shared__ __align__(16) char sm[32768];
  const int tid = threadIdx.x;
  const int lid = tid & 63, w = tid >> 6;     // w in 0..7
  const int l15 = lid & 15, lg = lid >> 4;
  const int lr = lid >> 3, lu = lid & 7;
  const int swz8 = (lu ^ lr) << 3;

  // XCD-grouped remap over 9 qblks x 64 (b,h): f = xcd(3b) + 8*( gi*9 + qp )
  const int f = blockIdx.x;
  const int low = f & 7, j = f >> 3;
  const int gi = j / 9, qp = j - gi * 9;
  const int g = gi * 8 + low;          // (b,h) group
  const int h = g & 7, b = g >> 3;
  const int qblk = (qp < 5) ? (4 + qp) : (qp - 5);  // long (17-chunk) first
  const int bh = b * HH + h;
  const int q0w = qblk * 128 + w * 16;
  const u16* kbase = kh + (size_t)bh * SS * 64;
  const u16* vbase = vt + (size_t)bh * DH * SSP;

  bf8 qf[2];
  {
    int row = q0w + l15; if (row >= SS) row = SS - 1;
    const u16* qp_ = qh + ((size_t)bh * SS + row) * 64;
    qf[0] = *reinterpret_cast<const bf8*>(qp_ + lg * 8);
    qf[1] = *reinterpret_cast<const bf8*>(qp_ + 32 + lg * 8);
  }
  const int qrow = q0w + l15;   // this lane's query (for mask + softmax state)

  float m_q = -1e30f, l_q = 0.f;
  f32x4 accO[3] = {};

  const int nch = (qblk < 4) ? 9 : 17;

  auto stage = [&](int bsel, int c) {
    const int j0 = c * 64;
    char* kb = sm + bsel * 16384;
    char* vb = kb + 8192;
    {
      int s = w * 8 + lr;
      int jt_ = s >> 4, lgs = (s >> 2) & 3, rr = s & 3;
      int p = ((jt_ >> 1) << 5) + (lgs << 3) + ((jt_ & 1) << 2) + rr;  // pi(s)
      int jrow = j0 + p; if (jrow >= SS) jrow = SS - 1;
      async16(kb + w * 1024, kbase + (size_t)jrow * 64 + swz8);
    }
    {
      int vrow = w * 8 + lr; if (vrow >= DH) vrow = DH - 1;
      async16(vb + w * 1024, vbase + (size_t)vrow * SSP + j0 + swz8);
    }
  };

  stage(0, 0);
  __syncthreads();          // prologue: full drain, buf0 ready
  int bsel = 0;

  for (int c = 0; c < nch; ++c) {
    if (c + 1 < nch) {
      stage(bsel ^ 1, c + 1);                           // 2 loads in flight
      asm volatile("s_waitcnt vmcnt(2)" ::: "memory");  // chunk c landed
    } else {
      asm volatile("s_waitcnt vmcnt(0)" ::: "memory");
    }
    __builtin_amdgcn_s_barrier();                       // all waves' chunk c visible
    const int j0 = c * 64;
    const char* kb = sm + bsel * 16384;
    const char* vb = kb + 8192;

    // QK^T swapped: sv[jt][r] = S[pi-slot = jt*16+lg*4+r][q = l15]
    f32x4 sv[4];
    __builtin_amdgcn_s_setprio(1);
#pragma unroll
    for (int jt = 0; jt < 4; ++jt) {
      int row = jt * 16 + l15;
      int off0 = ((row << 7) + (lg << 4)) ^ ((row & 7) << 4);
      int off1 = ((row << 7) + 64 + (lg << 4)) ^ ((row & 7) << 4);
      bf8 kb0 = *reinterpret_cast<const bf8*>(kb + off0);
      bf8 kb1 = *reinterpret_cast<const bf8*>(kb + off1);
      f32x4 z = {};
      z = __builtin_amdgcn_mfma_f32_16x16x32_bf16(kb0, qf[0], z, 0, 0, 0);
      z = __builtin_amdgcn_mfma_f32_16x16x32_bf16(kb1, qf[1], z, 0, 0, 0);
      sv[jt] = z;
    }
    __builtin_amdgcn_s_setprio(0);

    const bool domask = (c == 16) | ((q0w < NM1) & (c >= 8));
    if (domask) {
#pragma unroll
      for (int jt = 0; jt < 4; ++jt)
#pragma unroll
        for (int r = 0; r < 4; ++r) {
          int kabs = j0 + ((jt >> 1) << 5) + (lg << 3) + ((jt & 1) << 2) + r;
          if (kabs >= SS || (qrow < NM1 && kabs >= NM1)) sv[jt][r] = -1e30f;
        }
    }

    // row max: max3 tree + 2 cross-group shfl
    float mx = max3f(sv[0][0], sv[0][1], sv[0][2]);
    mx = max3f(mx, sv[0][3], sv[1][0]);
    mx = max3f(mx, sv[1][1], sv[1][2]);
    mx = max3f(mx, sv[1][3], sv[2][0]);
    mx = max3f(mx, sv[2][1], sv[2][2]);
    mx = max3f(mx, sv[2][3], sv[3][0]);
    mx = max3f(mx, sv[3][1], sv[3][2]);
    mx = fmaxf(mx, sv[3][3]);
    mx = fmaxf(mx, __shfl_xor(mx, 16));
    mx = fmaxf(mx, __shfl_xor(mx, 32));

    const bool skip = __all(mx <= m_q);   // T13: no new max anywhere -> no rescale
    const float mn = skip ? m_q : fmaxf(m_q, mx);

    // exp2 domain (scores pre-scaled by log2e): p = 2^(s - mn)
    float pv[4][4];
    float ps = 0.f;
#pragma unroll
    for (int jt = 0; jt < 4; ++jt)
#pragma unroll
      for (int r = 0; r < 4; ++r) {
        float p = __builtin_amdgcn_exp2f(sv[jt][r] - mn);
        pv[jt][r] = p;
        ps += p;
      }
    ps += __shfl_xor(ps, 16);
    ps += __shfl_xor(ps, 32);

    if (!skip) {
      float alpha = __builtin_amdgcn_exp2f(m_q - mn);
      l_q = l_q * alpha + ps;
      m_q = mn;
      const int lg4 = lg * 4;
      float a0 = __shfl(alpha, lg4);
      float a1 = __shfl(alpha, lg4 + 1);
      float a2 = __shfl(alpha, lg4 + 2);
      float a3 = __shfl(alpha, lg4 + 3);
#pragma unroll
      for (int dt = 0; dt < 3; ++dt) {
        accO[dt][0] *= a0; accO[dt][1] *= a1;
        accO[dt][2] *= a2; accO[dt][3] *= a3;
      }
    } else {
      l_q += ps;
    }

    // pa[jc][i] = pv[jc*2 + (i>>2)][i&3] -- pure in-lane bf16 pack
    bf8 pa[2];
#pragma unroll
    for (int jc = 0; jc < 2; ++jc) {
      u32 w0 = (u32)f2bf(pv[jc * 2][0])     | ((u32)f2bf(pv[jc * 2][1]) << 16);
      u32 w1 = (u32)f2bf(pv[jc * 2][2])     | ((u32)f2bf(pv[jc * 2][3]) << 16);
      u32 w2 = (u32)f2bf(pv[jc * 2 + 1][0]) | ((u32)f2bf(pv[jc * 2 + 1][1]) << 16);
      u32 w3 = (u32)f2bf(pv[jc * 2 + 1][2]) | ((u32)f2bf(pv[jc * 2 + 1][3]) << 16);
      uint4 t = make_uint4(w0, w1, w2, w3);
      pa[jc] = *reinterpret_cast<bf8*>(&t);
    }

    // PV from LDS Vt tile (natural key order matches pi via construction)
    __builtin_amdgcn_s_setprio(1);
#pragma unroll
    for (int dt = 0; dt < 3; ++dt) {
      int row = dt * 16 + l15;
#pragma unroll
      for (int jc = 0; jc < 2; ++jc) {
        int off = ((row << 7) + (jc << 6) + (lg << 4)) ^ ((row & 7) << 4);
        bf8 vb8 = *reinterpret_cast<const bf8*>(vb + off);
        accO[dt] = __builtin_amdgcn_mfma_f32_16x16x32_bf16(pa[jc], vb8, accO[dt], 0, 0, 0);
      }
    }
    __builtin_amdgcn_s_setprio(0);
    asm volatile("s_waitcnt lgkmcnt(0)" ::: "memory");  // buf bsel reads done
    __builtin_amdgcn_s_barrier();                       // WAR: buf free for c+2
    bsel ^= 1;
  }

  // epilogue: fetch 1/l for the 4 output rows (q = q0w + lg*4 + r)
  float linv = 1.0f / l_q;
  const int lg4 = lg * 4;
  float il[4];
#pragma unroll
  for (int r = 0; r < 4; ++r) il[r] = __shfl(linv, lg4 + r);
#pragma unroll
  for (int r = 0; r < 4; ++r) {
    int q = q0w + lg4 + r;
    if (q >= SS) continue;
#pragma unroll
    for (int dt = 0; dt < 3; ++dt) {
      int d = dt * 16 + l15;
      outb[((size_t)(b * SS + q)) * DD + h * DH + d] = f2bf(accO[dt][r] * il[r]);
    }
  }
}

// ---------------------------------------------------------------------------
// out = LayerNorm(a) * g + be; ONE WAVE PER ROW (no LDS, no barriers).
// Block 512 = 8 rows; each lane handles 6 elements (384/64).
// ---------------------------------------------------------------------------
__global__ __launch_bounds__(512) void add_ln(const float* __restrict__ a,
                                              const float* __restrict__ g,
                                              const float* __restrict__ be,
                                              float* __restrict__ out,
                                              u16* __restrict__ outb) {
  const int w = threadIdx.x >> 6, lane = threadIdx.x & 63;
  const int row = blockIdx.x * 8 + w;          // MROWS = 8272 = 8*1034 exactly
  const size_t base = (size_t)row * DD;
  float x[6];
#pragma unroll
  for (int jj = 0; jj < 6; ++jj) x[jj] = a[base + lane + 64 * jj];
  float s = x[0] + x[1] + x[2] + x[3] + x[4] + x[5];
#pragma unroll
  for (int off = 32; off; off >>= 1) s += __shfl_xor(s, off);
  float mean = s * (1.0f / 384.0f);
  float dv[6], vs = 0.f;
#pragma unroll
  for (int jj = 0; jj < 6; ++jj) { dv[jj] = x[jj] - mean; vs += dv[jj] * dv[jj]; }
#pragma unroll
  for (int off = 32; off; off >>= 1) vs += __shfl_xor(vs, off);
  float rs = rsqrtf(vs * (1.0f / 384.0f) + 1e-5f);
#pragma unroll
  for (int jj = 0; jj < 6; ++jj) {
    int c = lane + 64 * jj;
    float o = dv[jj] * rs * g[c] + be[c];
    out[base + c] = o;
    outb[base + c] = f2bf(o);
  }
}

__global__ void copy_out(const float* __restrict__ src, float* __restrict__ out) {
  int idx = blockIdx.x * 256 + threadIdx.x;
  if (idx >= BB * TT * DD) return;
  int d = idx % DD;
  int bt = idx / DD;
  int t = bt % TT;
  int b = bt / TT;
  out[idx] = src[((size_t)b * SS + (SS - TT) + t) * DD + d];
}

// ---------------------------------------------------------------------------
extern "C" void kernel_launch(void* const* d_in, const int* in_sizes, int n_in,
                              void* d_out, int out_size, void* d_ws, size_t ws_size,
                              hipStream_t stream) {
  const float* hand_t    = (const float*)d_in[0];
  const float* head_t    = (const float*)d_in[1];
  const float* hand_m1   = (const float*)d_in[2];
  const float* head_m1   = (const float*)d_in[3];
  const float* c_hand_t  = (const float*)d_in[4];
  const float* c_head_t  = (const float*)d_in[5];
  const float* c_hand_m1 = (const float*)d_in[6];
  const float* c_head_m1 = (const float*)d_in[7];
  const float* state_t   = (const float*)d_in[8];
  const float* state_m1  = (const float*)d_in[9];
  const float* tr_t      = (const float*)d_in[10];
  const float* tr_m1     = (const float*)d_in[11];
  const float* tok_m1    = (const float*)d_in[12];
  const float* tok_t     = (const float*)d_in[13];
  const float* Wq = (const float*)d_in[14];
  const float* bq = (const float*)d_in[15];
  const float* Wk = (const float*)d_in[16];
  const float* bk = (const float*)d_in[17];
  const float* Wv = (const float*)d_in[18];
  const float* bv = (const float*)d_in[19];
  const float* Wo = (const float*)d_in[20];
  const float* bo = (const float*)d_in[21];
  const float* W1 = (const float*)d_in[22];
  const float* b1 = (const float*)d_in[23];
  const float* W2 = (const float*)d_in[24];
  const float* b2 = (const float*)d_in[25];
  const float* g1 = (const float*)d_in[26];
  const float* be1 = (const float*)d_in[27];
  const float* g2 = (const float*)d_in[28];
  const float* be2 = (const float*)d_in[29];

  const size_t SRC_N = (size_t)BB * SS * DD;       // 3,176,448
  float* src    = (float*)d_ws;
  float* src2   = src + SRC_N;
  float* bufB   = src2 + SRC_N;
  float* coords = bufB + SRC_N;                    // 24,816
  float* bqkv   = coords + (size_t)BB * SS * 3;    // L*1152
  float2* trig  = (float2*)(bqkv + (size_t)LL * NQKV);   // B*S*24 float2
  u16* srcb  = (u16*)(trig + (size_t)BB * SS * 24);
  u16* src2b = srcb + SRC_N;
  u16* attnb = src2b + SRC_N;
  u16* qh  = attnb + SRC_N;
  const size_t QH_N = (size_t)BB * HH * SS * 64;   // 4,233,216
  u16* khb = qh + QH_N;
  u16* vtb = khb + QH_N;                           // 64*48*1088
  u16* hbf = vtb + (size_t)64 * DH * SSP;          // 12,705,792
  u16* wqkv_b = hbf + (size_t)MROWS * FFD;
  const size_t WD = (size_t)LL * DD * DD;
  const size_t WF = (size_t)LL * FFD * DD;
  u16* wo_bf = wqkv_b + (size_t)LL * NQKV * 384;
  u16* w1_bf = wo_bf + WD;
  u16* w2_bf = w1_bf + WF;

  dim3 blk(256);
  dim3 blk512(512);

  build_src<<<(BB * SS * DD + 255) / 256, blk, 0, stream>>>(
      hand_t, head_t, hand_m1, head_m1, state_t, state_m1, tok_m1, tok_t, src, srcb);
  build_coords<<<(BB * SS * 3 + 255) / 256, blk, 0, stream>>>(
      c_hand_t, c_head_t, c_hand_m1, c_head_m1, tr_t, tr_m1, coords);
  build_trig<<<(BB * SS * 24 + 255) / 256, blk, 0, stream>>>(coords, trig);
  pack_qkv<<<(LL * NQKV * 96 + 255) / 256, blk, 0, stream>>>(Wq, Wk, Wv, wqkv_b);
  pack_bqkv<<<(LL * NQKV + 255) / 256, blk, 0, stream>>>(bq, bk, bv, bqkv);
  cvt_bf<<<(int)(WD / 4 + 255) / 256, blk, 0, stream>>>(Wo, wo_bf, (int)(WD / 4));
  cvt_bf<<<(int)(WF / 4 + 255) / 256, blk, 0, stream>>>(W1, w1_bf, (int)(WF / 4));
  cvt_bf<<<(int)(WF / 4 + 255) / 256, blk, 0, stream>>>(W2, w2_bf, (int)(WF / 4));
  pad_vt<<<(64 * DH * (SSP - SS) + 255) / 256, blk, 0, stream>>>(vtb);
  pad_qk<<<(64 * SS * 16 + 255) / 256, blk, 0, stream>>>(qh, khb);

  // balanced XCD M-stripe grids: nxt * 72 (9 slots per XCD; XCD0 uses 9,
  // XCD1..7 use 8 -> early-exit on the 9th)
  dim3 gqkv(18 * 72);   // N=1152
  dim3 gwo(6 * 72);     // N=384
  dim3 gf1(24 * 72);    // N=1536
  dim3 gf2(6 * 72);     // N=384
  dim3 gattn(9 * 8 * 8);  // 9 qblks of 128 queries x 64 (b,h)

  for (int l = 0; l < LL; ++l) {
    const u16* Wqkv_l = wqkv_b + (size_t)l * NQKV * 384;
    const u16* Wo_l = wo_bf + (size_t)l * DD * DD;
    const u16* W1_l = w1_bf + (size_t)l * FFD * DD;
    const u16* W2_l = w2_bf + (size_t)l * DD * FFD;

    gemm_as<0, 2, NQKV, DD><<<gqkv, blk512, 0, stream>>>(
        srcb, Wqkv_l, bqkv + l * NQKV, trig, nullptr, nullptr, qh, khb, vtb);
    attn_mfma<<<gattn, blk512, 0, stream>>>(qh, khb, vtb, attnb);
    gemm_as<0, 0, DD, DD><<<gwo, blk512, 0, stream>>>(
        attnb, Wo_l, bo + l * DD, nullptr, src, bufB, nullptr, nullptr, nullptr);
    add_ln<<<MROWS / 8, blk512, 0, stream>>>(bufB, g1 + l * DD, be1 + l * DD, src2, src2b);
    gemm_as<1, 1, FFD, DD><<<gf1, blk512, 0, stream>>>(
        src2b, W1_l, b1 + l * FFD, nullptr, nullptr, nullptr, hbf, nullptr, nullptr);
    gemm_as<0, 0, DD, FFD><<<gf2, blk512, 0, stream>>>(
        hbf, W2_l, b2 + l * DD, nullptr, src2, bufB, nullptr, nullptr, nullptr);
    add_ln<<<MROWS / 8, blk512, 0, stream>>>(bufB, g2 + l * DD, be2 + l * DD, src, srcb);
  }
  copy_out<<<(BB * TT * DD + 255) / 256, blk, 0, stream>>>(src, (float*)d_out);
}